// Round 1
// baseline (16391.838 us; speedup 1.0000x reference)
//
#include <hip/hip_runtime.h>

#define DD 64
#define LL 5
#define GG 512
#define AFN 9
#define AVN 120
#define BFN 3
#define BVN 6
#define BNEPS 1e-5f

// ---------------- atom encoder: h[i] = sum_f atom_emb[f][x_feats[i,f]] ----------------
__global__ __launch_bounds__(256) void k_atom(
    const int* __restrict__ xf, const float* __restrict__ aemb,
    float* __restrict__ h, int N)
{
  int t = blockIdx.x * 256 + threadIdx.x;
  int row = t >> 4, c4 = t & 15;   // 16 threads per row, float4 each
  if (row >= N) return;
  const int* x = xf + row * AFN;
  float4 s = make_float4(0.f, 0.f, 0.f, 0.f);
  #pragma unroll
  for (int f = 0; f < AFN; ++f) {
    int v = x[f];
    float4 w = ((const float4*)aemb)[(f * AVN + v) * 16 + c4];
    s.x += w.x; s.y += w.y; s.z += w.z; s.w += w.w;
  }
  ((float4*)h)[row * 16 + c4] = s;
}

// ---------------- edge scatter: agg[col] += relu(h[row] + bond_emb(edge)) ----------------
__global__ __launch_bounds__(256) void k_scatter(
    const float* __restrict__ h, const int* __restrict__ ei,
    const int* __restrict__ ea, const float* __restrict__ bemb,
    float* __restrict__ agg, int E)
{
  int t = blockIdx.x * 256 + threadIdx.x;
  int e = t >> 4, c4 = t & 15;
  if (e >= E) return;
  int r = ei[e];
  int c = ei[E + e];
  int a0 = ea[e * 3 + 0], a1 = ea[e * 3 + 1], a2 = ea[e * 3 + 2];
  float4 v  = ((const float4*)h)[(size_t)r * 16 + c4];
  float4 e0 = ((const float4*)bemb)[(0 * BVN + a0) * 16 + c4];
  float4 e1 = ((const float4*)bemb)[(1 * BVN + a1) * 16 + c4];
  float4 e2 = ((const float4*)bemb)[(2 * BVN + a2) * 16 + c4];
  float m0 = fmaxf(v.x + e0.x + e1.x + e2.x, 0.f);
  float m1 = fmaxf(v.y + e0.y + e1.y + e2.y, 0.f);
  float m2 = fmaxf(v.z + e0.z + e1.z + e2.z, 0.f);
  float m3 = fmaxf(v.w + e0.w + e1.w + e2.w, 0.f);
  float* dst = agg + (size_t)c * DD + c4 * 4;
  atomicAdd(dst + 0, m0);
  atomicAdd(dst + 1, m1);
  atomicAdd(dst + 2, m2);
  atomicAdd(dst + 3, m3);
}

// wave(64)-reduce of a float4 (sum and sumsq) then atomic into stats
__device__ inline void wave_stats(float4 val, float* __restrict__ sum_dst,
                                  float* __restrict__ sq_dst, int jb, int lane)
{
  float sx = val.x, sy = val.y, sz = val.z, sw = val.w;
  float qx = val.x * val.x, qy = val.y * val.y, qz = val.z * val.z, qw = val.w * val.w;
  #pragma unroll
  for (int o = 32; o >= 1; o >>= 1) {
    sx += __shfl_xor(sx, o); sy += __shfl_xor(sy, o);
    sz += __shfl_xor(sz, o); sw += __shfl_xor(sw, o);
    qx += __shfl_xor(qx, o); qy += __shfl_xor(qy, o);
    qz += __shfl_xor(qz, o); qw += __shfl_xor(qw, o);
  }
  if (lane == 0) {
    atomicAdd(sum_dst + jb * 4 + 0, sx);
    atomicAdd(sum_dst + jb * 4 + 1, sy);
    atomicAdd(sum_dst + jb * 4 + 2, sz);
    atomicAdd(sum_dst + jb * 4 + 3, sw);
    atomicAdd(sq_dst + jb * 4 + 0, qx);
    atomicAdd(sq_dst + jb * 4 + 1, qy);
    atomicAdd(sq_dst + jb * 4 + 2, qz);
    atomicAdd(sq_dst + jb * 4 + 3, qw);
  }
}

// ---------------- mlp1: z1 = ((1+eps)h + agg) @ W1 + b1, accumulate stats ----------------
__global__ __launch_bounds__(256) void k_mlp1(
    const float* __restrict__ h, float* __restrict__ buf,
    const float* __restrict__ W, const float* __restrict__ b,
    const float* __restrict__ epsl, float* __restrict__ stats, int N)
{
  __shared__ float Wl[DD * DD];
  for (int i = threadIdx.x; i < DD * DD; i += 256) Wl[i] = W[i];
  __syncthreads();
  int row = blockIdx.x * 256 + threadIdx.x;
  bool act = row < N;
  int lane = threadIdx.x & 63;
  float epsv = 1.f + epsl[0];
  float x[DD];
  if (act) {
    const float4* h4 = (const float4*)(h + (size_t)row * DD);
    const float4* a4 = (const float4*)(buf + (size_t)row * DD);
    #pragma unroll
    for (int q = 0; q < 16; ++q) {
      float4 hv = h4[q], av = a4[q];
      x[q * 4 + 0] = epsv * hv.x + av.x;
      x[q * 4 + 1] = epsv * hv.y + av.y;
      x[q * 4 + 2] = epsv * hv.z + av.z;
      x[q * 4 + 3] = epsv * hv.w + av.w;
    }
  } else {
    #pragma unroll
    for (int k = 0; k < DD; ++k) x[k] = 0.f;
  }
  const float4* W4 = (const float4*)Wl;
  float4* o4 = (float4*)(buf + (size_t)row * DD);
  for (int jb = 0; jb < 16; ++jb) {
    float ax = 0.f, ay = 0.f, az = 0.f, aw = 0.f;
    #pragma unroll
    for (int k = 0; k < DD; ++k) {
      float4 w = W4[k * 16 + jb];
      ax = fmaf(x[k], w.x, ax);
      ay = fmaf(x[k], w.y, ay);
      az = fmaf(x[k], w.z, az);
      aw = fmaf(x[k], w.w, aw);
    }
    float4 res = make_float4(0.f, 0.f, 0.f, 0.f);
    if (act) {
      float4 bb = ((const float4*)b)[jb];
      res = make_float4(ax + bb.x, ay + bb.y, az + bb.z, aw + bb.w);
      o4[jb] = res;
    }
    wave_stats(res, stats, stats + DD, jb, lane);
  }
}

// ---------------- mlp2: z2 = relu(BN1(z1)) @ W2 + b2, accumulate stats2 ----------------
__global__ __launch_bounds__(256) void k_mlp2(
    float* __restrict__ buf, const float* __restrict__ W, const float* __restrict__ b,
    const float* __restrict__ g1, const float* __restrict__ b1g,
    const float* __restrict__ statsIn, float* __restrict__ statsOut,
    int N, float invN)
{
  __shared__ float Wl[DD * DD];
  __shared__ float sc[DD], sh[DD];
  for (int i = threadIdx.x; i < DD * DD; i += 256) Wl[i] = W[i];
  if (threadIdx.x < DD) {
    int j = threadIdx.x;
    float m = statsIn[j] * invN;
    float v = statsIn[DD + j] * invN - m * m;
    float inv = rsqrtf(v + BNEPS);
    float scale = inv * g1[j];
    sc[j] = scale;
    sh[j] = b1g[j] - m * scale;
  }
  __syncthreads();
  int row = blockIdx.x * 256 + threadIdx.x;
  bool act = row < N;
  int lane = threadIdx.x & 63;
  float x[DD];
  if (act) {
    const float* in = buf + (size_t)row * DD;
    #pragma unroll
    for (int k = 0; k < DD; ++k)
      x[k] = fmaxf(in[k] * sc[k] + sh[k], 0.f);
  } else {
    #pragma unroll
    for (int k = 0; k < DD; ++k) x[k] = 0.f;
  }
  const float4* W4 = (const float4*)Wl;
  float4* o4 = (float4*)(buf + (size_t)row * DD);
  for (int jb = 0; jb < 16; ++jb) {
    float ax = 0.f, ay = 0.f, az = 0.f, aw = 0.f;
    #pragma unroll
    for (int k = 0; k < DD; ++k) {
      float4 w = W4[k * 16 + jb];
      ax = fmaf(x[k], w.x, ax);
      ay = fmaf(x[k], w.y, ay);
      az = fmaf(x[k], w.z, az);
      aw = fmaf(x[k], w.w, aw);
    }
    float4 res = make_float4(0.f, 0.f, 0.f, 0.f);
    if (act) {
      float4 bb = ((const float4*)b)[jb];
      res = make_float4(ax + bb.x, ay + bb.y, az + bb.z, aw + bb.w);
      o4[jb] = res;
    }
    wave_stats(res, statsOut, statsOut + DD, jb, lane);
  }
}

// ---------------- bnout: h = BN2(z2) (+relu unless last), fp[g,l,:] += h ----------------
__global__ __launch_bounds__(256) void k_bnout(
    const float* __restrict__ buf, float* __restrict__ h,
    const float* __restrict__ g2, const float* __restrict__ b2g,
    const float* __restrict__ statsIn, const int* __restrict__ batch,
    float* __restrict__ fp, float* __restrict__ outp,
    int l, int N, float invN)
{
  __shared__ float sc[DD], sh[DD];
  if (threadIdx.x < DD) {
    int j = threadIdx.x;
    float m = statsIn[j] * invN;
    float v = statsIn[DD + j] * invN - m * m;
    float inv = rsqrtf(v + BNEPS);
    float scale = inv * g2[j];
    sc[j] = scale;
    sh[j] = b2g[j] - m * scale;
  }
  __syncthreads();
  int row = blockIdx.x * 256 + threadIdx.x;
  if (row >= N) return;
  int g = batch[row];
  float* fpdst = fp + ((size_t)g * LL + l) * DD;
  const float4* in4 = (const float4*)(buf + (size_t)row * DD);
  float4* h4 = (float4*)(h + (size_t)row * DD);
  bool last = (l == LL - 1);
  #pragma unroll
  for (int q = 0; q < 16; ++q) {
    float4 z = in4[q];
    float4 y;
    y.x = z.x * sc[q * 4 + 0] + sh[q * 4 + 0];
    y.y = z.y * sc[q * 4 + 1] + sh[q * 4 + 1];
    y.z = z.z * sc[q * 4 + 2] + sh[q * 4 + 2];
    y.w = z.w * sc[q * 4 + 3] + sh[q * 4 + 3];
    if (!last) {
      y.x = fmaxf(y.x, 0.f); y.y = fmaxf(y.y, 0.f);
      y.z = fmaxf(y.z, 0.f); y.w = fmaxf(y.w, 0.f);
    }
    h4[q] = y;
    if (last) ((float4*)outp)[(size_t)row * 16 + q] = y;
    atomicAdd(fpdst + q * 4 + 0, y.x);
    atomicAdd(fpdst + q * 4 + 1, y.y);
    atomicAdd(fpdst + q * 4 + 2, y.z);
    atomicAdd(fpdst + q * 4 + 3, y.w);
  }
}

extern "C" void kernel_launch(void* const* d_in, const int* in_sizes, int n_in,
                              void* d_out, int out_size, void* d_ws, size_t ws_size,
                              hipStream_t stream)
{
  const int*   x_feats    = (const int*)d_in[0];
  const int*   edge_index = (const int*)d_in[1];
  const int*   edge_attr  = (const int*)d_in[2];
  const int*   batch      = (const int*)d_in[3];
  const float* atom_emb   = (const float*)d_in[4];
  const float* bond_emb   = (const float*)d_in[5];
  const float* eps        = (const float*)d_in[6];
  const float* W1         = (const float*)d_in[7];
  const float* b1         = (const float*)d_in[8];
  const float* bn1_g      = (const float*)d_in[9];
  const float* bn1_b      = (const float*)d_in[10];
  const float* W2         = (const float*)d_in[11];
  const float* b2         = (const float*)d_in[12];
  const float* bn_g       = (const float*)d_in[13];
  const float* bn_b       = (const float*)d_in[14];

  int N  = in_sizes[3];
  int E  = in_sizes[1] / 2;
  float invN = 1.f / (float)N;

  float* out = (float*)d_out;
  float* fp  = out + (size_t)N * DD;              // [G, L, D]

  float* h     = (float*)d_ws;                    // N*D
  float* buf   = h + (size_t)N * DD;              // N*D (agg -> z1 -> z2)
  float* stats = buf + (size_t)N * DD;            // L * 256 floats

  hipMemsetAsync(stats, 0, LL * 256 * sizeof(float), stream);
  hipMemsetAsync(fp, 0, (size_t)GG * LL * DD * sizeof(float), stream);

  k_atom<<<(N * 16 + 255) / 256, 256, 0, stream>>>(x_feats, atom_emb, h, N);

  int mlp_grid = (N + 255) / 256;
  for (int l = 0; l < LL; ++l) {
    hipMemsetAsync(buf, 0, (size_t)N * DD * sizeof(float), stream);
    k_scatter<<<(E * 16 + 255) / 256, 256, 0, stream>>>(
        h, edge_index, edge_attr, bond_emb + (size_t)l * BFN * BVN * DD, buf, E);
    float* s1 = stats + l * 256;
    float* s2 = s1 + 128;
    k_mlp1<<<mlp_grid, 256, 0, stream>>>(h, buf, W1 + (size_t)l * DD * DD,
                                         b1 + l * DD, eps + l, s1, N);
    k_mlp2<<<mlp_grid, 256, 0, stream>>>(buf, W2 + (size_t)l * DD * DD,
                                         b2 + l * DD, bn1_g + l * DD, bn1_b + l * DD,
                                         s1, s2, N, invN);
    k_bnout<<<mlp_grid, 256, 0, stream>>>(buf, h, bn_g + l * DD, bn_b + l * DD,
                                          s2, batch, fp, out, l, N, invN);
  }
}

// Round 2
// 1294.044 us; speedup vs baseline: 12.6671x; 12.6671x over previous
//
#include <hip/hip_runtime.h>

#define DD 64
#define LL 5
#define GG 512
#define AFN 9
#define AVN 120
#define BFN 3
#define BVN 6
#define BNEPS 1e-5f
#define SCB 1024

// ---------------- atom encoder: h[i] = sum_f atom_emb[f][x_feats[i,f]] ----------------
__global__ __launch_bounds__(256) void k_atom(
    const int* __restrict__ xf, const float* __restrict__ aemb,
    float* __restrict__ h, int N)
{
  int t = blockIdx.x * 256 + threadIdx.x;
  int row = t >> 4, c4 = t & 15;
  if (row >= N) return;
  const int* x = xf + row * AFN;
  float4 s = make_float4(0.f, 0.f, 0.f, 0.f);
  #pragma unroll
  for (int f = 0; f < AFN; ++f) {
    int v = x[f];
    float4 w = ((const float4*)aemb)[(f * AVN + v) * 16 + c4];
    s.x += w.x; s.y += w.y; s.z += w.z; s.w += w.w;
  }
  ((float4*)h)[row * 16 + c4] = s;
}

// ---------------- CSR build ----------------
__global__ __launch_bounds__(256) void k_hist(const int* __restrict__ ei,
    int* __restrict__ deg, int E)
{
  int t = blockIdx.x * 256 + threadIdx.x;
  if (t >= E) return;
  atomicAdd(&deg[ei[E + t]], 1);
}

__global__ __launch_bounds__(1024) void k_scan1(const int* __restrict__ deg,
    int* __restrict__ scanned, int* __restrict__ bsum, int N)
{
  __shared__ int s[SCB];
  int i = blockIdx.x * SCB + threadIdx.x;
  int x = (i < N) ? deg[i] : 0;
  s[threadIdx.x] = x;
  for (int off = 1; off < SCB; off <<= 1) {
    __syncthreads();
    int v = (threadIdx.x >= off) ? s[threadIdx.x - off] : 0;
    __syncthreads();
    s[threadIdx.x] += v;
  }
  __syncthreads();
  if (i < N) scanned[i] = s[threadIdx.x] - x;   // exclusive within block
  if (threadIdx.x == SCB - 1) bsum[blockIdx.x] = s[SCB - 1];
}

__global__ __launch_bounds__(128) void k_scan2(const int* __restrict__ bsum,
    int* __restrict__ boff, int NB)
{
  __shared__ int s[128];
  int x = (threadIdx.x < NB) ? bsum[threadIdx.x] : 0;
  s[threadIdx.x] = x;
  for (int off = 1; off < 128; off <<= 1) {
    __syncthreads();
    int v = (threadIdx.x >= off) ? s[threadIdx.x - off] : 0;
    __syncthreads();
    s[threadIdx.x] += v;
  }
  __syncthreads();
  if (threadIdx.x < NB) boff[threadIdx.x] = s[threadIdx.x] - x;  // exclusive
}

__global__ __launch_bounds__(256) void k_fill(const int* __restrict__ ei,
    const int* __restrict__ ea, const int* __restrict__ scanned,
    const int* __restrict__ boff, int* __restrict__ cursor,
    int* __restrict__ rcarr, int E)
{
  int t = blockIdx.x * 256 + threadIdx.x;
  if (t >= E) return;
  int r = ei[t], c = ei[E + t];
  int code = ea[t * 3 + 0] + ea[t * 3 + 1] * 6 + ea[t * 3 + 2] * 36;
  int base = scanned[c] + boff[c >> 10];
  int pos = base + atomicAdd(&cursor[c], 1);
  rcarr[pos] = r | (code << 20);
}

// precompute combined bond embeddings: bcomb[l][code][ch], code in [0,216)
__global__ __launch_bounds__(256) void k_bcomb(const float* __restrict__ bemb,
    float* __restrict__ bcomb)
{
  int t = blockIdx.x * 256 + threadIdx.x;
  if (t >= LL * 216 * DD) return;
  int ch = t & 63;
  int cl = t >> 6;
  int code = cl % 216;
  int l = cl / 216;
  int a0 = code % 6, a1 = (code / 6) % 6, a2 = code / 36;
  const float* B = bemb + (size_t)l * BFN * BVN * DD;
  bcomb[t] = B[(0 * BVN + a0) * DD + ch] + B[(1 * BVN + a1) * DD + ch]
           + B[(2 * BVN + a2) * DD + ch];
}

// graph boundaries (batch is sorted): gs[g] = first idx with batch[idx] >= g
__global__ __launch_bounds__(256) void k_bounds(const int* __restrict__ batch,
    int* __restrict__ gs, int N)
{
  int g = blockIdx.x * 256 + threadIdx.x;
  if (g > GG) return;
  int lo = 0, hi = N;
  while (lo < hi) { int mid = (lo + hi) >> 1; if (batch[mid] < g) lo = mid + 1; else hi = mid; }
  gs[g] = lo;
}

// ---------------- per-layer aggregate: wave per node, no atomics ----------------
__global__ __launch_bounds__(256) void k_gather(
    const float* __restrict__ h, const int* __restrict__ rcarr,
    const int* __restrict__ scanned, const int* __restrict__ boff,
    const float* __restrict__ bc, float* __restrict__ agg, int N, int E)
{
  int lane = threadIdx.x & 63;
  int node = blockIdx.x * 4 + (threadIdx.x >> 6);
  if (node >= N) return;
  int s = scanned[node] + boff[node >> 10];
  int e = (node + 1 < N) ? (scanned[node + 1] + boff[(node + 1) >> 10]) : E;
  float acc = 0.f;
  for (int k0 = s; k0 < e; k0 += 64) {
    int rc = 0;
    if (k0 + lane < e) rc = rcarr[k0 + lane];
    int m = min(64, e - k0);
    for (int kk = 0; kk < m; ++kk) {
      int rck = __shfl(rc, kk);
      int r = rck & 0xFFFFF;
      int code = rck >> 20;
      float hv = h[(size_t)r * DD + lane];
      float bv = bc[code * DD + lane];
      acc += fmaxf(hv + bv, 0.f);
    }
  }
  agg[(size_t)node * DD + lane] = acc;
}

// wave(64)-reduce of a float4 (sum and sumsq) then LDS atomic
__device__ inline void wave_stats_lds(float4 val, float* __restrict__ ssum,
                                      float* __restrict__ ssq, int jb, int lane)
{
  float sx = val.x, sy = val.y, sz = val.z, sw = val.w;
  float qx = val.x * val.x, qy = val.y * val.y, qz = val.z * val.z, qw = val.w * val.w;
  #pragma unroll
  for (int o = 32; o >= 1; o >>= 1) {
    sx += __shfl_xor(sx, o); sy += __shfl_xor(sy, o);
    sz += __shfl_xor(sz, o); sw += __shfl_xor(sw, o);
    qx += __shfl_xor(qx, o); qy += __shfl_xor(qy, o);
    qz += __shfl_xor(qz, o); qw += __shfl_xor(qw, o);
  }
  if (lane == 0) {
    atomicAdd(&ssum[jb * 4 + 0], sx);
    atomicAdd(&ssum[jb * 4 + 1], sy);
    atomicAdd(&ssum[jb * 4 + 2], sz);
    atomicAdd(&ssum[jb * 4 + 3], sw);
    atomicAdd(&ssq[jb * 4 + 0], qx);
    atomicAdd(&ssq[jb * 4 + 1], qy);
    atomicAdd(&ssq[jb * 4 + 2], qz);
    atomicAdd(&ssq[jb * 4 + 3], qw);
  }
}

// ---------------- mlp1: z1 = ((1+eps)h + agg) @ W1 + b1, accumulate stats ----------------
__global__ __launch_bounds__(256) void k_mlp1(
    const float* __restrict__ h, float* __restrict__ buf,
    const float* __restrict__ W, const float* __restrict__ b,
    const float* __restrict__ epsl, float* __restrict__ stats, int N)
{
  __shared__ float Wl[DD * DD];
  __shared__ float ssum[DD], ssq[DD];
  if (threadIdx.x < DD) { ssum[threadIdx.x] = 0.f; ssq[threadIdx.x] = 0.f; }
  for (int i = threadIdx.x; i < DD * DD; i += 256) Wl[i] = W[i];
  __syncthreads();
  int row = blockIdx.x * 256 + threadIdx.x;
  bool act = row < N;
  int lane = threadIdx.x & 63;
  float epsv = 1.f + epsl[0];
  float x[DD];
  if (act) {
    const float4* h4 = (const float4*)(h + (size_t)row * DD);
    const float4* a4 = (const float4*)(buf + (size_t)row * DD);
    #pragma unroll
    for (int q = 0; q < 16; ++q) {
      float4 hv = h4[q], av = a4[q];
      x[q * 4 + 0] = epsv * hv.x + av.x;
      x[q * 4 + 1] = epsv * hv.y + av.y;
      x[q * 4 + 2] = epsv * hv.z + av.z;
      x[q * 4 + 3] = epsv * hv.w + av.w;
    }
  } else {
    #pragma unroll
    for (int k = 0; k < DD; ++k) x[k] = 0.f;
  }
  const float4* W4 = (const float4*)Wl;
  float4* o4 = (float4*)(buf + (size_t)row * DD);
  for (int jb = 0; jb < 16; ++jb) {
    float ax = 0.f, ay = 0.f, az = 0.f, aw = 0.f;
    #pragma unroll
    for (int k = 0; k < DD; ++k) {
      float4 w = W4[k * 16 + jb];
      ax = fmaf(x[k], w.x, ax);
      ay = fmaf(x[k], w.y, ay);
      az = fmaf(x[k], w.z, az);
      aw = fmaf(x[k], w.w, aw);
    }
    float4 res = make_float4(0.f, 0.f, 0.f, 0.f);
    if (act) {
      float4 bb = ((const float4*)b)[jb];
      res = make_float4(ax + bb.x, ay + bb.y, az + bb.z, aw + bb.w);
      o4[jb] = res;
    }
    wave_stats_lds(res, ssum, ssq, jb, lane);
  }
  __syncthreads();
  if (threadIdx.x < DD) {
    atomicAdd(&stats[threadIdx.x], ssum[threadIdx.x]);
    atomicAdd(&stats[DD + threadIdx.x], ssq[threadIdx.x]);
  }
}

// ---------------- mlp2: z2 = relu(BN1(z1)) @ W2 + b2, accumulate stats2 ----------------
__global__ __launch_bounds__(256) void k_mlp2(
    float* __restrict__ buf, const float* __restrict__ W, const float* __restrict__ b,
    const float* __restrict__ g1, const float* __restrict__ b1g,
    const float* __restrict__ statsIn, float* __restrict__ statsOut,
    int N, float invN)
{
  __shared__ float Wl[DD * DD];
  __shared__ float sc[DD], sh[DD];
  __shared__ float ssum[DD], ssq[DD];
  if (threadIdx.x < DD) { ssum[threadIdx.x] = 0.f; ssq[threadIdx.x] = 0.f; }
  for (int i = threadIdx.x; i < DD * DD; i += 256) Wl[i] = W[i];
  if (threadIdx.x < DD) {
    int j = threadIdx.x;
    float m = statsIn[j] * invN;
    float v = statsIn[DD + j] * invN - m * m;
    float inv = rsqrtf(v + BNEPS);
    float scale = inv * g1[j];
    sc[j] = scale;
    sh[j] = b1g[j] - m * scale;
  }
  __syncthreads();
  int row = blockIdx.x * 256 + threadIdx.x;
  bool act = row < N;
  int lane = threadIdx.x & 63;
  float x[DD];
  if (act) {
    const float* in = buf + (size_t)row * DD;
    #pragma unroll
    for (int k = 0; k < DD; ++k)
      x[k] = fmaxf(in[k] * sc[k] + sh[k], 0.f);
  } else {
    #pragma unroll
    for (int k = 0; k < DD; ++k) x[k] = 0.f;
  }
  const float4* W4 = (const float4*)Wl;
  float4* o4 = (float4*)(buf + (size_t)row * DD);
  for (int jb = 0; jb < 16; ++jb) {
    float ax = 0.f, ay = 0.f, az = 0.f, aw = 0.f;
    #pragma unroll
    for (int k = 0; k < DD; ++k) {
      float4 w = W4[k * 16 + jb];
      ax = fmaf(x[k], w.x, ax);
      ay = fmaf(x[k], w.y, ay);
      az = fmaf(x[k], w.z, az);
      aw = fmaf(x[k], w.w, aw);
    }
    float4 res = make_float4(0.f, 0.f, 0.f, 0.f);
    if (act) {
      float4 bb = ((const float4*)b)[jb];
      res = make_float4(ax + bb.x, ay + bb.y, az + bb.z, aw + bb.w);
      o4[jb] = res;
    }
    wave_stats_lds(res, ssum, ssq, jb, lane);
  }
  __syncthreads();
  if (threadIdx.x < DD) {
    atomicAdd(&statsOut[threadIdx.x], ssum[threadIdx.x]);
    atomicAdd(&statsOut[DD + threadIdx.x], ssq[threadIdx.x]);
  }
}

// ---------------- bnout + fingerprint: block per graph (batch sorted) ----------------
__global__ __launch_bounds__(256) void k_bnout_fp(
    const float* __restrict__ buf, float* __restrict__ h,
    const float* __restrict__ g2, const float* __restrict__ b2g,
    const float* __restrict__ statsIn, const int* __restrict__ gs,
    float* __restrict__ fp, float* __restrict__ outp,
    int l, float invN)
{
  __shared__ float sc[DD], sh[DD], part[4 * DD];
  int tid = threadIdx.x;
  if (tid < DD) {
    float m = statsIn[tid] * invN;
    float v = statsIn[DD + tid] * invN - m * m;
    float inv = rsqrtf(v + BNEPS);
    float scale = inv * g2[tid];
    sc[tid] = scale;
    sh[tid] = b2g[tid] - m * scale;
  }
  __syncthreads();
  int g = blockIdx.x;
  int r0 = gs[g], r1 = gs[g + 1];
  int ch = tid & 63, rg = tid >> 6;
  bool last = (l == LL - 1);
  float facc = 0.f;
  for (int r = r0 + rg; r < r1; r += 4) {
    float z = buf[(size_t)r * DD + ch];
    float y = z * sc[ch] + sh[ch];
    if (!last) y = fmaxf(y, 0.f);
    h[(size_t)r * DD + ch] = y;
    if (last) outp[(size_t)r * DD + ch] = y;
    facc += y;
  }
  part[rg * DD + ch] = facc;
  __syncthreads();
  if (tid < DD) {
    float s = part[tid] + part[DD + tid] + part[2 * DD + tid] + part[3 * DD + tid];
    fp[((size_t)g * LL + l) * DD + tid] = s;
  }
}

extern "C" void kernel_launch(void* const* d_in, const int* in_sizes, int n_in,
                              void* d_out, int out_size, void* d_ws, size_t ws_size,
                              hipStream_t stream)
{
  const int*   x_feats    = (const int*)d_in[0];
  const int*   edge_index = (const int*)d_in[1];
  const int*   edge_attr  = (const int*)d_in[2];
  const int*   batch      = (const int*)d_in[3];
  const float* atom_emb   = (const float*)d_in[4];
  const float* bond_emb   = (const float*)d_in[5];
  const float* eps        = (const float*)d_in[6];
  const float* W1         = (const float*)d_in[7];
  const float* b1         = (const float*)d_in[8];
  const float* bn1_g      = (const float*)d_in[9];
  const float* bn1_b      = (const float*)d_in[10];
  const float* W2         = (const float*)d_in[11];
  const float* b2         = (const float*)d_in[12];
  const float* bn_g       = (const float*)d_in[13];
  const float* bn_b       = (const float*)d_in[14];

  int N = in_sizes[3];
  int E = in_sizes[1] / 2;
  int NB = (N + SCB - 1) / SCB;
  float invN = 1.f / (float)N;

  float* out = (float*)d_out;
  float* fp  = out + (size_t)N * DD;

  float* h       = (float*)d_ws;                 // N*D
  float* buf     = h + (size_t)N * DD;           // N*D
  float* stats   = buf + (size_t)N * DD;         // L*256
  float* bcomb   = stats + LL * 256;             // L*216*D
  int* deg       = (int*)(bcomb + LL * 216 * DD);// N
  int* cursor    = deg + N;                      // N
  int* scanned   = cursor + N;                   // N
  int* bsum      = scanned + N;                  // 128
  int* boff      = bsum + 128;                   // 128
  int* gs        = boff + 128;                   // G+1
  int* rcarr     = gs + (GG + 1);                // E

  hipMemsetAsync(stats, 0, LL * 256 * sizeof(float), stream);
  hipMemsetAsync(deg, 0, 2 * (size_t)N * sizeof(int), stream);  // deg + cursor

  k_atom<<<(N * 16 + 255) / 256, 256, 0, stream>>>(x_feats, atom_emb, h, N);
  k_hist<<<(E + 255) / 256, 256, 0, stream>>>(edge_index, deg, E);
  k_scan1<<<NB, SCB, 0, stream>>>(deg, scanned, bsum, N);
  k_scan2<<<1, 128, 0, stream>>>(bsum, boff, NB);
  k_fill<<<(E + 255) / 256, 256, 0, stream>>>(edge_index, edge_attr, scanned,
                                              boff, cursor, rcarr, E);
  k_bcomb<<<(LL * 216 * DD + 255) / 256, 256, 0, stream>>>(bond_emb, bcomb);
  k_bounds<<<(GG + 256) / 256, 256, 0, stream>>>(batch, gs, N);

  int mlp_grid = (N + 255) / 256;
  for (int l = 0; l < LL; ++l) {
    float* s1 = stats + l * 256;
    float* s2 = s1 + 128;
    k_gather<<<(N + 3) / 4, 256, 0, stream>>>(h, rcarr, scanned, boff,
                                              bcomb + (size_t)l * 216 * DD, buf, N, E);
    k_mlp1<<<mlp_grid, 256, 0, stream>>>(h, buf, W1 + (size_t)l * DD * DD,
                                         b1 + l * DD, eps + l, s1, N);
    k_mlp2<<<mlp_grid, 256, 0, stream>>>(buf, W2 + (size_t)l * DD * DD,
                                         b2 + l * DD, bn1_g + l * DD, bn1_b + l * DD,
                                         s1, s2, N, invN);
    k_bnout_fp<<<GG, 256, 0, stream>>>(buf, h, bn_g + l * DD, bn_b + l * DD,
                                       s2, gs, fp, out, l, invN);
  }
}

// Round 3
// 1154.337 us; speedup vs baseline: 14.2002x; 1.1210x over previous
//
#include <hip/hip_runtime.h>

#define DD 64
#define LL 5
#define GG 512
#define AFN 9
#define AVN 120
#define BFN 3
#define BVN 6
#define BNEPS 1e-5f
#define SCB 1024

typedef unsigned int uint;
typedef unsigned short ushort;

__device__ inline ushort f2bf(float f) {
  uint u = __float_as_uint(f);
  uint r = (u + 0x7FFF + ((u >> 16) & 1)) >> 16;   // round-to-nearest-even
  return (ushort)r;
}

// ---------------- atom encoder: h[i] = sum_f atom_emb[f][x_feats[i,f]] ----------------
__global__ __launch_bounds__(256) void k_atom(
    const int* __restrict__ xf, const float* __restrict__ aemb,
    float* __restrict__ h, ushort* __restrict__ h2, int N)
{
  int t = blockIdx.x * 256 + threadIdx.x;
  int row = t >> 4, c4 = t & 15;
  if (row >= N) return;
  const int* x = xf + row * AFN;
  float4 s = make_float4(0.f, 0.f, 0.f, 0.f);
  #pragma unroll
  for (int f = 0; f < AFN; ++f) {
    int v = x[f];
    float4 w = ((const float4*)aemb)[(f * AVN + v) * 16 + c4];
    s.x += w.x; s.y += w.y; s.z += w.z; s.w += w.w;
  }
  ((float4*)h)[row * 16 + c4] = s;
  ushort4 p;
  p.x = f2bf(s.x); p.y = f2bf(s.y); p.z = f2bf(s.z); p.w = f2bf(s.w);
  ((ushort4*)h2)[row * 16 + c4] = p;
}

// ---------------- CSR build ----------------
__global__ __launch_bounds__(256) void k_hist(const int* __restrict__ ei,
    int* __restrict__ deg, int E)
{
  int t = blockIdx.x * 256 + threadIdx.x;
  if (t >= E) return;
  atomicAdd(&deg[ei[E + t]], 1);
}

__global__ __launch_bounds__(1024) void k_scan1(const int* __restrict__ deg,
    int* __restrict__ scanned, int* __restrict__ bsum, int N)
{
  __shared__ int s[SCB];
  int i = blockIdx.x * SCB + threadIdx.x;
  int x = (i < N) ? deg[i] : 0;
  s[threadIdx.x] = x;
  for (int off = 1; off < SCB; off <<= 1) {
    __syncthreads();
    int v = (threadIdx.x >= off) ? s[threadIdx.x - off] : 0;
    __syncthreads();
    s[threadIdx.x] += v;
  }
  __syncthreads();
  if (i < N) scanned[i] = s[threadIdx.x] - x;
  if (threadIdx.x == SCB - 1) bsum[blockIdx.x] = s[SCB - 1];
}

__global__ __launch_bounds__(128) void k_scan2(const int* __restrict__ bsum,
    int* __restrict__ boff, int NB)
{
  __shared__ int s[128];
  int x = (threadIdx.x < NB) ? bsum[threadIdx.x] : 0;
  s[threadIdx.x] = x;
  for (int off = 1; off < 128; off <<= 1) {
    __syncthreads();
    int v = (threadIdx.x >= off) ? s[threadIdx.x - off] : 0;
    __syncthreads();
    s[threadIdx.x] += v;
  }
  __syncthreads();
  if (threadIdx.x < NB) boff[threadIdx.x] = s[threadIdx.x] - x;
}

__global__ __launch_bounds__(256) void k_fill(const int* __restrict__ ei,
    const int* __restrict__ ea, const int* __restrict__ scanned,
    const int* __restrict__ boff, int* __restrict__ cursor,
    int* __restrict__ rcarr, int E)
{
  int t = blockIdx.x * 256 + threadIdx.x;
  if (t >= E) return;
  int r = ei[t], c = ei[E + t];
  int code = ea[t * 3 + 0] + ea[t * 3 + 1] * 6 + ea[t * 3 + 2] * 36;
  int base = scanned[c] + boff[c >> 10];
  int pos = base + atomicAdd(&cursor[c], 1);
  rcarr[pos] = r | (code << 20);
}

// precompute combined bond embeddings: bcomb[l][code][ch]
__global__ __launch_bounds__(256) void k_bcomb(const float* __restrict__ bemb,
    float* __restrict__ bcomb)
{
  int t = blockIdx.x * 256 + threadIdx.x;
  if (t >= LL * 216 * DD) return;
  int ch = t & 63;
  int cl = t >> 6;
  int code = cl % 216;
  int l = cl / 216;
  int a0 = code % 6, a1 = (code / 6) % 6, a2 = code / 36;
  const float* B = bemb + (size_t)l * BFN * BVN * DD;
  bcomb[t] = B[(0 * BVN + a0) * DD + ch] + B[(1 * BVN + a1) * DD + ch]
           + B[(2 * BVN + a2) * DD + ch];
}

__global__ __launch_bounds__(256) void k_bounds(const int* __restrict__ batch,
    int* __restrict__ gs, int N)
{
  int g = blockIdx.x * 256 + threadIdx.x;
  if (g > GG) return;
  int lo = 0, hi = N;
  while (lo < hi) { int mid = (lo + hi) >> 1; if (batch[mid] < g) lo = mid + 1; else hi = mid; }
  gs[g] = lo;
}

// ---------------- per-layer aggregate: wave per node, bf16 h, 2 edges/iter ----------------
__global__ __launch_bounds__(256) void k_gather(
    const ushort* __restrict__ h2, const int* __restrict__ rcarr,
    const int* __restrict__ scanned, const int* __restrict__ boff,
    const float* __restrict__ bc, float* __restrict__ agg, int N, int E)
{
  int lane = threadIdx.x & 63;
  int node = blockIdx.x * 4 + (threadIdx.x >> 6);
  if (node >= N) return;
  int s = scanned[node] + boff[node >> 10];
  int e = (node + 1 < N) ? (scanned[node + 1] + boff[(node + 1) >> 10]) : E;
  int half = lane >> 5;     // which edge of the pair this lane handles
  int c2 = lane & 31;       // channel-pair index (channels 2*c2, 2*c2+1)
  float acc0 = 0.f, acc1 = 0.f;
  const uint* h2u = (const uint*)h2;
  const float2* bc2 = (const float2*)bc;
  for (int k0 = s; k0 < e; k0 += 64) {
    int rc = 0;
    if (k0 + lane < e) rc = rcarr[k0 + lane];
    int m = min(64, e - k0);
    for (int kk = 0; kk < m; kk += 2) {
      int idx = kk + half;
      int rck = __shfl(rc, idx);
      int r = rck & 0xFFFFF;
      int code = (rck >> 20) & 0xFFF;
      uint hv = h2u[r * 32 + c2];
      float2 bv = bc2[code * 32 + c2];
      float f0 = __uint_as_float(hv << 16);
      float f1 = __uint_as_float(hv & 0xFFFF0000u);
      float m0 = fmaxf(f0 + bv.x, 0.f);
      float m1 = fmaxf(f1 + bv.y, 0.f);
      if (idx < m) { acc0 += m0; acc1 += m1; }
    }
  }
  acc0 += __shfl_xor(acc0, 32);
  acc1 += __shfl_xor(acc1, 32);
  if (half == 0)
    ((float2*)agg)[(size_t)node * 32 + c2] = make_float2(acc0, acc1);
}

// wave(64)-reduce of a float4 (sum and sumsq) then LDS atomic
__device__ inline void wave_stats_lds(float4 val, float* __restrict__ ssum,
                                      float* __restrict__ ssq, int jb, int lane)
{
  float sx = val.x, sy = val.y, sz = val.z, sw = val.w;
  float qx = val.x * val.x, qy = val.y * val.y, qz = val.z * val.z, qw = val.w * val.w;
  #pragma unroll
  for (int o = 32; o >= 1; o >>= 1) {
    sx += __shfl_xor(sx, o); sy += __shfl_xor(sy, o);
    sz += __shfl_xor(sz, o); sw += __shfl_xor(sw, o);
    qx += __shfl_xor(qx, o); qy += __shfl_xor(qy, o);
    qz += __shfl_xor(qz, o); qw += __shfl_xor(qw, o);
  }
  if (lane == 0) {
    atomicAdd(&ssum[jb * 4 + 0], sx);
    atomicAdd(&ssum[jb * 4 + 1], sy);
    atomicAdd(&ssum[jb * 4 + 2], sz);
    atomicAdd(&ssum[jb * 4 + 3], sw);
    atomicAdd(&ssq[jb * 4 + 0], qx);
    atomicAdd(&ssq[jb * 4 + 1], qy);
    atomicAdd(&ssq[jb * 4 + 2], qz);
    atomicAdd(&ssq[jb * 4 + 3], qw);
  }
}

// ---------------- mlp1: z1 = ((1+eps)h + agg) @ W1 + b1, accumulate stats ----------------
__global__ __launch_bounds__(256) void k_mlp1(
    const float* __restrict__ h, float* __restrict__ buf,
    const float* __restrict__ W, const float* __restrict__ b,
    const float* __restrict__ epsl, float* __restrict__ stats, int N)
{
  __shared__ float Wl[DD * DD];
  __shared__ float ssum[DD], ssq[DD];
  if (threadIdx.x < DD) { ssum[threadIdx.x] = 0.f; ssq[threadIdx.x] = 0.f; }
  for (int i = threadIdx.x; i < DD * DD; i += 256) Wl[i] = W[i];
  __syncthreads();
  int row = blockIdx.x * 256 + threadIdx.x;
  bool act = row < N;
  int lane = threadIdx.x & 63;
  float epsv = 1.f + epsl[0];
  float x[DD];
  if (act) {
    const float4* h4 = (const float4*)(h + (size_t)row * DD);
    const float4* a4 = (const float4*)(buf + (size_t)row * DD);
    #pragma unroll
    for (int q = 0; q < 16; ++q) {
      float4 hv = h4[q], av = a4[q];
      x[q * 4 + 0] = epsv * hv.x + av.x;
      x[q * 4 + 1] = epsv * hv.y + av.y;
      x[q * 4 + 2] = epsv * hv.z + av.z;
      x[q * 4 + 3] = epsv * hv.w + av.w;
    }
  } else {
    #pragma unroll
    for (int k = 0; k < DD; ++k) x[k] = 0.f;
  }
  const float4* W4 = (const float4*)Wl;
  float4* o4 = (float4*)(buf + (size_t)row * DD);
  for (int jb = 0; jb < 16; ++jb) {
    float ax = 0.f, ay = 0.f, az = 0.f, aw = 0.f;
    #pragma unroll
    for (int k = 0; k < DD; ++k) {
      float4 w = W4[k * 16 + jb];
      ax = fmaf(x[k], w.x, ax);
      ay = fmaf(x[k], w.y, ay);
      az = fmaf(x[k], w.z, az);
      aw = fmaf(x[k], w.w, aw);
    }
    float4 res = make_float4(0.f, 0.f, 0.f, 0.f);
    if (act) {
      float4 bb = ((const float4*)b)[jb];
      res = make_float4(ax + bb.x, ay + bb.y, az + bb.z, aw + bb.w);
      o4[jb] = res;
    }
    wave_stats_lds(res, ssum, ssq, jb, lane);
  }
  __syncthreads();
  if (threadIdx.x < DD) {
    atomicAdd(&stats[threadIdx.x], ssum[threadIdx.x]);
    atomicAdd(&stats[DD + threadIdx.x], ssq[threadIdx.x]);
  }
}

// ---------------- mlp2: z2 = relu(BN1(z1)) @ W2 + b2, accumulate stats2 ----------------
__global__ __launch_bounds__(256) void k_mlp2(
    float* __restrict__ buf, const float* __restrict__ W, const float* __restrict__ b,
    const float* __restrict__ g1, const float* __restrict__ b1g,
    const float* __restrict__ statsIn, float* __restrict__ statsOut,
    int N, float invN)
{
  __shared__ float Wl[DD * DD];
  __shared__ float sc[DD], sh[DD];
  __shared__ float ssum[DD], ssq[DD];
  if (threadIdx.x < DD) { ssum[threadIdx.x] = 0.f; ssq[threadIdx.x] = 0.f; }
  for (int i = threadIdx.x; i < DD * DD; i += 256) Wl[i] = W[i];
  if (threadIdx.x < DD) {
    int j = threadIdx.x;
    float m = statsIn[j] * invN;
    float v = statsIn[DD + j] * invN - m * m;
    float inv = rsqrtf(v + BNEPS);
    float scale = inv * g1[j];
    sc[j] = scale;
    sh[j] = b1g[j] - m * scale;
  }
  __syncthreads();
  int row = blockIdx.x * 256 + threadIdx.x;
  bool act = row < N;
  int lane = threadIdx.x & 63;
  float x[DD];
  if (act) {
    const float* in = buf + (size_t)row * DD;
    #pragma unroll
    for (int k = 0; k < DD; ++k)
      x[k] = fmaxf(in[k] * sc[k] + sh[k], 0.f);
  } else {
    #pragma unroll
    for (int k = 0; k < DD; ++k) x[k] = 0.f;
  }
  const float4* W4 = (const float4*)Wl;
  float4* o4 = (float4*)(buf + (size_t)row * DD);
  for (int jb = 0; jb < 16; ++jb) {
    float ax = 0.f, ay = 0.f, az = 0.f, aw = 0.f;
    #pragma unroll
    for (int k = 0; k < DD; ++k) {
      float4 w = W4[k * 16 + jb];
      ax = fmaf(x[k], w.x, ax);
      ay = fmaf(x[k], w.y, ay);
      az = fmaf(x[k], w.z, az);
      aw = fmaf(x[k], w.w, aw);
    }
    float4 res = make_float4(0.f, 0.f, 0.f, 0.f);
    if (act) {
      float4 bb = ((const float4*)b)[jb];
      res = make_float4(ax + bb.x, ay + bb.y, az + bb.z, aw + bb.w);
      o4[jb] = res;
    }
    wave_stats_lds(res, ssum, ssq, jb, lane);
  }
  __syncthreads();
  if (threadIdx.x < DD) {
    atomicAdd(&statsOut[threadIdx.x], ssum[threadIdx.x]);
    atomicAdd(&statsOut[DD + threadIdx.x], ssq[threadIdx.x]);
  }
}

// ---------------- bnout + fingerprint: block per graph (batch sorted) ----------------
__global__ __launch_bounds__(256) void k_bnout_fp(
    const float* __restrict__ buf, float* __restrict__ h, ushort* __restrict__ h2,
    const float* __restrict__ g2, const float* __restrict__ b2g,
    const float* __restrict__ statsIn, const int* __restrict__ gs,
    float* __restrict__ fp, float* __restrict__ outp,
    int l, float invN)
{
  __shared__ float sc[DD], sh[DD], part[4 * DD];
  int tid = threadIdx.x;
  if (tid < DD) {
    float m = statsIn[tid] * invN;
    float v = statsIn[DD + tid] * invN - m * m;
    float inv = rsqrtf(v + BNEPS);
    float scale = inv * g2[tid];
    sc[tid] = scale;
    sh[tid] = b2g[tid] - m * scale;
  }
  __syncthreads();
  int g = blockIdx.x;
  int r0 = gs[g], r1 = gs[g + 1];
  int ch = tid & 63, rg = tid >> 6;
  bool last = (l == LL - 1);
  float facc = 0.f;
  for (int r = r0 + rg; r < r1; r += 4) {
    float z = buf[(size_t)r * DD + ch];
    float y = z * sc[ch] + sh[ch];
    if (!last) y = fmaxf(y, 0.f);
    h[(size_t)r * DD + ch] = y;
    if (!last) h2[(size_t)r * DD + ch] = f2bf(y);
    if (last) outp[(size_t)r * DD + ch] = y;
    facc += y;
  }
  part[rg * DD + ch] = facc;
  __syncthreads();
  if (tid < DD) {
    float s = part[tid] + part[DD + tid] + part[2 * DD + tid] + part[3 * DD + tid];
    fp[((size_t)g * LL + l) * DD + tid] = s;
  }
}

extern "C" void kernel_launch(void* const* d_in, const int* in_sizes, int n_in,
                              void* d_out, int out_size, void* d_ws, size_t ws_size,
                              hipStream_t stream)
{
  const int*   x_feats    = (const int*)d_in[0];
  const int*   edge_index = (const int*)d_in[1];
  const int*   edge_attr  = (const int*)d_in[2];
  const int*   batch      = (const int*)d_in[3];
  const float* atom_emb   = (const float*)d_in[4];
  const float* bond_emb   = (const float*)d_in[5];
  const float* eps        = (const float*)d_in[6];
  const float* W1         = (const float*)d_in[7];
  const float* b1         = (const float*)d_in[8];
  const float* bn1_g      = (const float*)d_in[9];
  const float* bn1_b      = (const float*)d_in[10];
  const float* W2         = (const float*)d_in[11];
  const float* b2         = (const float*)d_in[12];
  const float* bn_g       = (const float*)d_in[13];
  const float* bn_b       = (const float*)d_in[14];

  int N = in_sizes[3];
  int E = in_sizes[1] / 2;
  int NB = (N + SCB - 1) / SCB;
  float invN = 1.f / (float)N;

  float* out = (float*)d_out;
  float* fp  = out + (size_t)N * DD;

  float* h       = (float*)d_ws;                 // N*D fp32
  float* buf     = h + (size_t)N * DD;           // N*D fp32
  float* stats   = buf + (size_t)N * DD;         // L*256
  float* bcomb   = stats + LL * 256;             // L*216*D
  ushort* h2     = (ushort*)(bcomb + LL * 216 * DD); // N*D bf16
  int* deg       = (int*)(h2 + (size_t)N * DD);  // N
  int* cursor    = deg + N;                      // N
  int* scanned   = cursor + N;                   // N
  int* bsum      = scanned + N;                  // 128
  int* boff      = bsum + 128;                   // 128
  int* gs        = boff + 128;                   // G+1
  int* rcarr     = gs + (GG + 1);                // E

  hipMemsetAsync(stats, 0, LL * 256 * sizeof(float), stream);
  hipMemsetAsync(deg, 0, 2 * (size_t)N * sizeof(int), stream);

  k_atom<<<(N * 16 + 255) / 256, 256, 0, stream>>>(x_feats, atom_emb, h, h2, N);
  k_hist<<<(E + 255) / 256, 256, 0, stream>>>(edge_index, deg, E);
  k_scan1<<<NB, SCB, 0, stream>>>(deg, scanned, bsum, N);
  k_scan2<<<1, 128, 0, stream>>>(bsum, boff, NB);
  k_fill<<<(E + 255) / 256, 256, 0, stream>>>(edge_index, edge_attr, scanned,
                                              boff, cursor, rcarr, E);
  k_bcomb<<<(LL * 216 * DD + 255) / 256, 256, 0, stream>>>(bond_emb, bcomb);
  k_bounds<<<(GG + 256) / 256, 256, 0, stream>>>(batch, gs, N);

  int mlp_grid = (N + 255) / 256;
  for (int l = 0; l < LL; ++l) {
    float* s1 = stats + l * 256;
    float* s2 = s1 + 128;
    k_gather<<<(N + 3) / 4, 256, 0, stream>>>(h2, rcarr, scanned, boff,
                                              bcomb + (size_t)l * 216 * DD, buf, N, E);
    k_mlp1<<<mlp_grid, 256, 0, stream>>>(h, buf, W1 + (size_t)l * DD * DD,
                                         b1 + l * DD, eps + l, s1, N);
    k_mlp2<<<mlp_grid, 256, 0, stream>>>(buf, W2 + (size_t)l * DD * DD,
                                         b2 + l * DD, bn1_g + l * DD, bn1_b + l * DD,
                                         s1, s2, N, invN);
    k_bnout_fp<<<GG, 256, 0, stream>>>(buf, h, h2, bn_g + l * DD, bn_b + l * DD,
                                       s2, gs, fp, out, l, invN);
  }
}

// Round 4
// 1113.787 us; speedup vs baseline: 14.7172x; 1.0364x over previous
//
#include <hip/hip_runtime.h>

#define DD 64
#define LL 5
#define GG 512
#define AFN 9
#define AVN 120
#define BFN 3
#define BVN 6
#define BNEPS 1e-5f
#define SCB 1024

typedef unsigned int uint;
typedef unsigned short ushort;

__device__ inline ushort f2bf(float f) {
  uint u = __float_as_uint(f);
  uint r = (u + 0x7FFF + ((u >> 16) & 1)) >> 16;   // round-to-nearest-even
  return (ushort)r;
}

// ---------------- atom encoder: h[i] = sum_f atom_emb[f][x_feats[i,f]] ----------------
__global__ __launch_bounds__(256) void k_atom(
    const int* __restrict__ xf, const float* __restrict__ aemb,
    float* __restrict__ h, ushort* __restrict__ h2, int N)
{
  int t = blockIdx.x * 256 + threadIdx.x;
  int row = t >> 4, c4 = t & 15;
  if (row >= N) return;
  const int* x = xf + row * AFN;
  float4 s = make_float4(0.f, 0.f, 0.f, 0.f);
  #pragma unroll
  for (int f = 0; f < AFN; ++f) {
    int v = x[f];
    float4 w = ((const float4*)aemb)[(f * AVN + v) * 16 + c4];
    s.x += w.x; s.y += w.y; s.z += w.z; s.w += w.w;
  }
  ((float4*)h)[row * 16 + c4] = s;
  ushort4 p;
  p.x = f2bf(s.x); p.y = f2bf(s.y); p.z = f2bf(s.z); p.w = f2bf(s.w);
  ((ushort4*)h2)[row * 16 + c4] = p;
}

// ---------------- CSR build ----------------
// hist: count degree AND record this edge's rank within its target segment
__global__ __launch_bounds__(256) void k_hist(const int* __restrict__ ei,
    int* __restrict__ deg, int* __restrict__ rank, int E)
{
  int t = blockIdx.x * 256 + threadIdx.x;
  if (t >= E) return;
  rank[t] = atomicAdd(&deg[ei[E + t]], 1);
}

__global__ __launch_bounds__(1024) void k_scan1(const int* __restrict__ deg,
    int* __restrict__ scanned, int* __restrict__ bsum, int N)
{
  __shared__ int s[SCB];
  int i = blockIdx.x * SCB + threadIdx.x;
  int x = (i < N) ? deg[i] : 0;
  s[threadIdx.x] = x;
  for (int off = 1; off < SCB; off <<= 1) {
    __syncthreads();
    int v = (threadIdx.x >= off) ? s[threadIdx.x - off] : 0;
    __syncthreads();
    s[threadIdx.x] += v;
  }
  __syncthreads();
  if (i < N) scanned[i] = s[threadIdx.x] - x;
  if (threadIdx.x == SCB - 1) bsum[blockIdx.x] = s[SCB - 1];
}

__global__ __launch_bounds__(128) void k_scan2(const int* __restrict__ bsum,
    int* __restrict__ boff, int NB)
{
  __shared__ int s[128];
  int x = (threadIdx.x < NB) ? bsum[threadIdx.x] : 0;
  s[threadIdx.x] = x;
  for (int off = 1; off < 128; off <<= 1) {
    __syncthreads();
    int v = (threadIdx.x >= off) ? s[threadIdx.x - off] : 0;
    __syncthreads();
    s[threadIdx.x] += v;
  }
  __syncthreads();
  if (threadIdx.x < NB) boff[threadIdx.x] = s[threadIdx.x] - x;
}

// fill: atomic-free placement using precomputed rank
__global__ __launch_bounds__(256) void k_fill(const int* __restrict__ ei,
    const int* __restrict__ ea, const int* __restrict__ scanned,
    const int* __restrict__ boff, const int* __restrict__ rank,
    int* __restrict__ rcarr, int E)
{
  int t = blockIdx.x * 256 + threadIdx.x;
  if (t >= E) return;
  int r = ei[t], c = ei[E + t];
  int code = ea[t * 3 + 0] + ea[t * 3 + 1] * 6 + ea[t * 3 + 2] * 36;
  int pos = scanned[c] + boff[c >> 10] + rank[t];
  rcarr[pos] = r | (code << 20);
}

// precompute combined bond embeddings: bcomb[l][code][ch]
__global__ __launch_bounds__(256) void k_bcomb(const float* __restrict__ bemb,
    float* __restrict__ bcomb)
{
  int t = blockIdx.x * 256 + threadIdx.x;
  if (t >= LL * 216 * DD) return;
  int ch = t & 63;
  int cl = t >> 6;
  int code = cl % 216;
  int l = cl / 216;
  int a0 = code % 6, a1 = (code / 6) % 6, a2 = code / 36;
  const float* B = bemb + (size_t)l * BFN * BVN * DD;
  bcomb[t] = B[(0 * BVN + a0) * DD + ch] + B[(1 * BVN + a1) * DD + ch]
           + B[(2 * BVN + a2) * DD + ch];
}

__global__ __launch_bounds__(256) void k_bounds(const int* __restrict__ batch,
    int* __restrict__ gs, int N)
{
  int g = blockIdx.x * 256 + threadIdx.x;
  if (g > GG) return;
  int lo = 0, hi = N;
  while (lo < hi) { int mid = (lo + hi) >> 1; if (batch[mid] < g) lo = mid + 1; else hi = mid; }
  gs[g] = lo;
}

// ---------------- per-layer aggregate: wave per node, bf16 h, 2 edges/iter ----------------
__global__ __launch_bounds__(256) void k_gather(
    const ushort* __restrict__ h2, const int* __restrict__ rcarr,
    const int* __restrict__ scanned, const int* __restrict__ boff,
    const float* __restrict__ bc, float* __restrict__ agg, int N, int E)
{
  int lane = threadIdx.x & 63;
  int node = blockIdx.x * 4 + (threadIdx.x >> 6);
  if (node >= N) return;
  int s = scanned[node] + boff[node >> 10];
  int e = (node + 1 < N) ? (scanned[node + 1] + boff[(node + 1) >> 10]) : E;
  int half = lane >> 5;
  int c2 = lane & 31;
  float acc0 = 0.f, acc1 = 0.f;
  const uint* h2u = (const uint*)h2;
  const float2* bc2 = (const float2*)bc;
  for (int k0 = s; k0 < e; k0 += 64) {
    int rc = 0;
    if (k0 + lane < e) rc = rcarr[k0 + lane];
    int m = min(64, e - k0);
    for (int kk = 0; kk < m; kk += 2) {
      int idx = kk + half;
      int rck = __shfl(rc, idx);
      int r = rck & 0xFFFFF;
      int code = (rck >> 20) & 0xFFF;
      uint hv = h2u[r * 32 + c2];
      float2 bv = bc2[code * 32 + c2];
      float f0 = __uint_as_float(hv << 16);
      float f1 = __uint_as_float(hv & 0xFFFF0000u);
      float m0 = fmaxf(f0 + bv.x, 0.f);
      float m1 = fmaxf(f1 + bv.y, 0.f);
      if (idx < m) { acc0 += m0; acc1 += m1; }
    }
  }
  acc0 += __shfl_xor(acc0, 32);
  acc1 += __shfl_xor(acc1, 32);
  if (half == 0)
    ((float2*)agg)[(size_t)node * 32 + c2] = make_float2(acc0, acc1);
}

// wave(64)-reduce of a float4 (sum and sumsq) then LDS atomic
__device__ inline void wave_stats_lds(float4 val, float* __restrict__ ssum,
                                      float* __restrict__ ssq, int jb, int lane)
{
  float sx = val.x, sy = val.y, sz = val.z, sw = val.w;
  float qx = val.x * val.x, qy = val.y * val.y, qz = val.z * val.z, qw = val.w * val.w;
  #pragma unroll
  for (int o = 32; o >= 1; o >>= 1) {
    sx += __shfl_xor(sx, o); sy += __shfl_xor(sy, o);
    sz += __shfl_xor(sz, o); sw += __shfl_xor(sw, o);
    qx += __shfl_xor(qx, o); qy += __shfl_xor(qy, o);
    qz += __shfl_xor(qz, o); qw += __shfl_xor(qw, o);
  }
  if (lane == 0) {
    atomicAdd(&ssum[jb * 4 + 0], sx);
    atomicAdd(&ssum[jb * 4 + 1], sy);
    atomicAdd(&ssum[jb * 4 + 2], sz);
    atomicAdd(&ssum[jb * 4 + 3], sw);
    atomicAdd(&ssq[jb * 4 + 0], qx);
    atomicAdd(&ssq[jb * 4 + 1], qy);
    atomicAdd(&ssq[jb * 4 + 2], qz);
    atomicAdd(&ssq[jb * 4 + 3], qw);
  }
}

// ---------------- mlp1: z1 = ((1+eps)h + agg) @ W1 + b1, accumulate stats ----------------
__global__ __launch_bounds__(256) void k_mlp1(
    const float* __restrict__ h, float* __restrict__ buf,
    const float* __restrict__ W, const float* __restrict__ b,
    const float* __restrict__ epsl, float* __restrict__ stats, int N)
{
  __shared__ float Wl[DD * DD];
  __shared__ float ssum[DD], ssq[DD];
  if (threadIdx.x < DD) { ssum[threadIdx.x] = 0.f; ssq[threadIdx.x] = 0.f; }
  for (int i = threadIdx.x; i < DD * DD; i += 256) Wl[i] = W[i];
  __syncthreads();
  int row = blockIdx.x * 256 + threadIdx.x;
  bool act = row < N;
  int lane = threadIdx.x & 63;
  float epsv = 1.f + epsl[0];
  float x[DD];
  if (act) {
    const float4* h4 = (const float4*)(h + (size_t)row * DD);
    const float4* a4 = (const float4*)(buf + (size_t)row * DD);
    #pragma unroll
    for (int q = 0; q < 16; ++q) {
      float4 hv = h4[q], av = a4[q];
      x[q * 4 + 0] = epsv * hv.x + av.x;
      x[q * 4 + 1] = epsv * hv.y + av.y;
      x[q * 4 + 2] = epsv * hv.z + av.z;
      x[q * 4 + 3] = epsv * hv.w + av.w;
    }
  } else {
    #pragma unroll
    for (int k = 0; k < DD; ++k) x[k] = 0.f;
  }
  const float4* W4 = (const float4*)Wl;
  float4* o4 = (float4*)(buf + (size_t)row * DD);
  for (int jb = 0; jb < 16; ++jb) {
    float ax = 0.f, ay = 0.f, az = 0.f, aw = 0.f;
    #pragma unroll
    for (int k = 0; k < DD; ++k) {
      float4 w = W4[k * 16 + jb];
      ax = fmaf(x[k], w.x, ax);
      ay = fmaf(x[k], w.y, ay);
      az = fmaf(x[k], w.z, az);
      aw = fmaf(x[k], w.w, aw);
    }
    float4 res = make_float4(0.f, 0.f, 0.f, 0.f);
    if (act) {
      float4 bb = ((const float4*)b)[jb];
      res = make_float4(ax + bb.x, ay + bb.y, az + bb.z, aw + bb.w);
      o4[jb] = res;
    }
    wave_stats_lds(res, ssum, ssq, jb, lane);
  }
  __syncthreads();
  if (threadIdx.x < DD) {
    atomicAdd(&stats[threadIdx.x], ssum[threadIdx.x]);
    atomicAdd(&stats[DD + threadIdx.x], ssq[threadIdx.x]);
  }
}

// ---------------- mlp2: z2 = relu(BN1(z1)) @ W2 + b2, accumulate stats2 ----------------
__global__ __launch_bounds__(256) void k_mlp2(
    float* __restrict__ buf, const float* __restrict__ W, const float* __restrict__ b,
    const float* __restrict__ g1, const float* __restrict__ b1g,
    const float* __restrict__ statsIn, float* __restrict__ statsOut,
    int N, float invN)
{
  __shared__ float Wl[DD * DD];
  __shared__ float sc[DD], sh[DD];
  __shared__ float ssum[DD], ssq[DD];
  if (threadIdx.x < DD) { ssum[threadIdx.x] = 0.f; ssq[threadIdx.x] = 0.f; }
  for (int i = threadIdx.x; i < DD * DD; i += 256) Wl[i] = W[i];
  if (threadIdx.x < DD) {
    int j = threadIdx.x;
    float m = statsIn[j] * invN;
    float v = statsIn[DD + j] * invN - m * m;
    float inv = rsqrtf(v + BNEPS);
    float scale = inv * g1[j];
    sc[j] = scale;
    sh[j] = b1g[j] - m * scale;
  }
  __syncthreads();
  int row = blockIdx.x * 256 + threadIdx.x;
  bool act = row < N;
  int lane = threadIdx.x & 63;
  float x[DD];
  if (act) {
    const float* in = buf + (size_t)row * DD;
    #pragma unroll
    for (int k = 0; k < DD; ++k)
      x[k] = fmaxf(in[k] * sc[k] + sh[k], 0.f);
  } else {
    #pragma unroll
    for (int k = 0; k < DD; ++k) x[k] = 0.f;
  }
  const float4* W4 = (const float4*)Wl;
  float4* o4 = (float4*)(buf + (size_t)row * DD);
  for (int jb = 0; jb < 16; ++jb) {
    float ax = 0.f, ay = 0.f, az = 0.f, aw = 0.f;
    #pragma unroll
    for (int k = 0; k < DD; ++k) {
      float4 w = W4[k * 16 + jb];
      ax = fmaf(x[k], w.x, ax);
      ay = fmaf(x[k], w.y, ay);
      az = fmaf(x[k], w.z, az);
      aw = fmaf(x[k], w.w, aw);
    }
    float4 res = make_float4(0.f, 0.f, 0.f, 0.f);
    if (act) {
      float4 bb = ((const float4*)b)[jb];
      res = make_float4(ax + bb.x, ay + bb.y, az + bb.z, aw + bb.w);
      o4[jb] = res;
    }
    wave_stats_lds(res, ssum, ssq, jb, lane);
  }
  __syncthreads();
  if (threadIdx.x < DD) {
    atomicAdd(&statsOut[threadIdx.x], ssum[threadIdx.x]);
    atomicAdd(&statsOut[DD + threadIdx.x], ssq[threadIdx.x]);
  }
}

// ---------------- bnout + fingerprint: block per graph (batch sorted) ----------------
__global__ __launch_bounds__(256) void k_bnout_fp(
    const float* __restrict__ buf, float* __restrict__ h, ushort* __restrict__ h2,
    const float* __restrict__ g2, const float* __restrict__ b2g,
    const float* __restrict__ statsIn, const int* __restrict__ gs,
    float* __restrict__ fp, float* __restrict__ outp,
    int l, float invN)
{
  __shared__ float sc[DD], sh[DD], part[4 * DD];
  int tid = threadIdx.x;
  if (tid < DD) {
    float m = statsIn[tid] * invN;
    float v = statsIn[DD + tid] * invN - m * m;
    float inv = rsqrtf(v + BNEPS);
    float scale = inv * g2[tid];
    sc[tid] = scale;
    sh[tid] = b2g[tid] - m * scale;
  }
  __syncthreads();
  int g = blockIdx.x;
  int r0 = gs[g], r1 = gs[g + 1];
  int ch = tid & 63, rg = tid >> 6;
  bool last = (l == LL - 1);
  float facc = 0.f;
  for (int r = r0 + rg; r < r1; r += 4) {
    float z = buf[(size_t)r * DD + ch];
    float y = z * sc[ch] + sh[ch];
    if (!last) y = fmaxf(y, 0.f);
    h[(size_t)r * DD + ch] = y;
    if (!last) h2[(size_t)r * DD + ch] = f2bf(y);
    if (last) outp[(size_t)r * DD + ch] = y;
    facc += y;
  }
  part[rg * DD + ch] = facc;
  __syncthreads();
  if (tid < DD) {
    float s = part[tid] + part[DD + tid] + part[2 * DD + tid] + part[3 * DD + tid];
    fp[((size_t)g * LL + l) * DD + tid] = s;
  }
}

extern "C" void kernel_launch(void* const* d_in, const int* in_sizes, int n_in,
                              void* d_out, int out_size, void* d_ws, size_t ws_size,
                              hipStream_t stream)
{
  const int*   x_feats    = (const int*)d_in[0];
  const int*   edge_index = (const int*)d_in[1];
  const int*   edge_attr  = (const int*)d_in[2];
  const int*   batch      = (const int*)d_in[3];
  const float* atom_emb   = (const float*)d_in[4];
  const float* bond_emb   = (const float*)d_in[5];
  const float* eps        = (const float*)d_in[6];
  const float* W1         = (const float*)d_in[7];
  const float* b1         = (const float*)d_in[8];
  const float* bn1_g      = (const float*)d_in[9];
  const float* bn1_b      = (const float*)d_in[10];
  const float* W2         = (const float*)d_in[11];
  const float* b2         = (const float*)d_in[12];
  const float* bn_g       = (const float*)d_in[13];
  const float* bn_b       = (const float*)d_in[14];

  int N = in_sizes[3];
  int E = in_sizes[1] / 2;
  int NB = (N + SCB - 1) / SCB;
  float invN = 1.f / (float)N;

  float* out = (float*)d_out;
  float* fp  = out + (size_t)N * DD;

  float* h       = (float*)d_ws;                 // N*D fp32
  float* buf     = h + (size_t)N * DD;           // N*D fp32
  float* stats   = buf + (size_t)N * DD;         // L*256
  float* bcomb   = stats + LL * 256;             // L*216*D
  ushort* h2     = (ushort*)(bcomb + LL * 216 * DD); // N*D bf16
  int* deg       = (int*)(h2 + (size_t)N * DD);  // N
  int* rank      = deg + N;                      // E
  int* scanned   = rank + E;                     // N
  int* bsum      = scanned + N;                  // 128
  int* boff      = bsum + 128;                   // 128
  int* gs        = boff + 128;                   // G+1
  int* rcarr     = gs + (GG + 1);                // E

  hipMemsetAsync(stats, 0, LL * 256 * sizeof(float), stream);
  hipMemsetAsync(deg, 0, (size_t)N * sizeof(int), stream);

  k_atom<<<(N * 16 + 255) / 256, 256, 0, stream>>>(x_feats, atom_emb, h, h2, N);
  k_hist<<<(E + 255) / 256, 256, 0, stream>>>(edge_index, deg, rank, E);
  k_scan1<<<NB, SCB, 0, stream>>>(deg, scanned, bsum, N);
  k_scan2<<<1, 128, 0, stream>>>(bsum, boff, NB);
  k_fill<<<(E + 255) / 256, 256, 0, stream>>>(edge_index, edge_attr, scanned,
                                              boff, rank, rcarr, E);
  k_bcomb<<<(LL * 216 * DD + 255) / 256, 256, 0, stream>>>(bond_emb, bcomb);
  k_bounds<<<(GG + 256) / 256, 256, 0, stream>>>(batch, gs, N);

  int mlp_grid = (N + 255) / 256;
  for (int l = 0; l < LL; ++l) {
    float* s1 = stats + l * 256;
    float* s2 = s1 + 128;
    k_gather<<<(N + 3) / 4, 256, 0, stream>>>(h2, rcarr, scanned, boff,
                                              bcomb + (size_t)l * 216 * DD, buf, N, E);
    k_mlp1<<<mlp_grid, 256, 0, stream>>>(h, buf, W1 + (size_t)l * DD * DD,
                                         b1 + l * DD, eps + l, s1, N);
    k_mlp2<<<mlp_grid, 256, 0, stream>>>(buf, W2 + (size_t)l * DD * DD,
                                         b2 + l * DD, bn1_g + l * DD, bn1_b + l * DD,
                                         s1, s2, N, invN);
    k_bnout_fp<<<GG, 256, 0, stream>>>(buf, h, h2, bn_g + l * DD, bn_b + l * DD,
                                       s2, gs, fp, out, l, invN);
  }
}